// Round 2
// baseline (392.315 us; speedup 1.0000x reference)
//
#include <hip/hip_runtime.h>

// Embedding gather:
//   indices: [16384, 50] int (flat 819200), values in [0, 1_000_000)
//   table:   [1_000_000, 64] float32  (256 MB)
//   out:     [16384, 50, 64] float32  (210 MB)
//
// R2 changes vs R1:
//  - 8 lanes per row, 2 independent float4 loads per thread (2x MLP/wave slot,
//    half the redundant broadcast index loads).
//  - Non-temporal stores for the output: it is write-once/never-read, and its
//    210 MB would otherwise evict table rows from L2/L3 (table == 256 MB ==
//    whole Infinity Cache). nt keeps the caches for the gathered reads.

typedef float f32x4 __attribute__((ext_vector_type(4)));

__global__ __launch_bounds__(256) void ShardedCXLEmbedding_gather(
    const int* __restrict__ indices,
    const f32x4* __restrict__ table,   // [num_emb * 16] float4
    f32x4* __restrict__ out,           // [n_rows * 16] float4
    int n_rows)
{
    int g   = blockIdx.x * 256 + threadIdx.x;  // one thread = 2 float4 of one row
    int row = g >> 3;                          // which lookup
    int c   = g & 7;                           // float4 pair id within row
    if (row < n_rows) {
        int e = indices[row];                  // 8 lanes broadcast-read same addr
        const f32x4* src = table + (long long)e * 16;
        f32x4 a = src[c];                      // bytes [c*16,      c*16+16)
        f32x4 b = src[c + 8];                  // bytes [128+c*16, ...)
        f32x4* dst = out + (long long)row * 16;
        __builtin_nontemporal_store(a, dst + c);
        __builtin_nontemporal_store(b, dst + c + 8);
    }
}

extern "C" void kernel_launch(void* const* d_in, const int* in_sizes, int n_in,
                              void* d_out, int out_size, void* d_ws, size_t ws_size,
                              hipStream_t stream) {
    const int*   indices = (const int*)d_in[0];
    const f32x4* table   = (const f32x4*)d_in[1];
    f32x4*       out     = (f32x4*)d_out;

    const int n_rows = in_sizes[0];            // 819200
    const long long n_threads = (long long)n_rows * 8;
    const int block = 256;
    const int grid  = (int)((n_threads + block - 1) / block);

    ShardedCXLEmbedding_gather<<<grid, block, 0, stream>>>(indices, table, out, n_rows);
}